// Round 3
// baseline (8182.143 us; speedup 1.0000x reference)
//
#include <hip/hip_runtime.h>

#define NB 128
#define NS 256
#define ND 1024
#define NH 1024
#define NT 20
#define NG 4096
#define START_IDX_ 19
#define NBLK 256u

typedef __bf16 v8bf __attribute__((ext_vector_type(8)));
typedef float v4f __attribute__((ext_vector_type(4)));
typedef unsigned int v4u __attribute__((ext_vector_type(4)));

static __device__ __forceinline__ unsigned short f2bf(float f){
  union { float f; unsigned u; } v; v.f = f;
  unsigned r = v.u + 0x7fffu + ((v.u >> 16) & 1u);
  return (unsigned short)(r >> 16);
}
static __device__ __forceinline__ float bf2f(unsigned short h){
  union { unsigned u; float f; } v; v.u = ((unsigned)h) << 16; return v.f;
}
static __device__ __forceinline__ float sigm(float x){ return 1.0f / (1.0f + __expf(-x)); }
static __device__ __forceinline__ float tanhf_(float x){ return 1.0f - 2.0f / (__expf(2.0f * x) + 1.0f); }

typedef __attribute__((address_space(1))) const unsigned int gu32_t;
typedef __attribute__((address_space(3))) unsigned int lu32_t;
static __device__ __forceinline__ void gload16(const void* g, void* l){
  __builtin_amdgcn_global_load_lds((gu32_t*)g, (lu32_t*)l, 16, 0, 0);
}
static __device__ __forceinline__ v4f mfma16x16x32(v8bf a, v8bf b, v4f c){
  return __builtin_amdgcn_mfma_f32_16x16x32_bf16(a, b, c, 0, 0, 0);
}

// ---- MALL-coherent (L0+L2 bypass) access helpers ----
static __device__ __forceinline__ v4u bypass_ld16(const void* p){
  v4u r; asm volatile("global_load_dwordx4 %0, %1, off sc0 sc1" : "=v"(r) : "v"(p)); return r;
}
static __device__ __forceinline__ void bypass_st16(void* p, v4u v){
  asm volatile("global_store_dwordx4 %0, %1, off sc0 sc1" :: "v"(p), "v"(v) : "memory");
}
static __device__ __forceinline__ void bypass_st2(void* p, unsigned v){
  asm volatile("global_store_short %0, %1, off sc0 sc1" :: "v"(p), "v"(v) : "memory");
}
static __device__ __forceinline__ void bypass_st4(void* p, unsigned v){
  asm volatile("global_store_dword %0, %1, off sc0 sc1" :: "v"(p), "v"(v) : "memory");
}
static __device__ __forceinline__ unsigned bypass_ld4_wait(const void* p){
  unsigned r;
  asm volatile("global_load_dword %0, %1, off sc0 sc1\n\ts_waitcnt vmcnt(0)"
               : "=v"(r) : "v"(p) : "memory");
  return r;
}
#define DRAIN_VM() { asm volatile("s_waitcnt vmcnt(0)" ::: "memory"); __builtin_amdgcn_sched_barrier(0); }

// ---- per-batch-group barrier: relaxed-only atomics, no fences ----
// per group (4KB region): sub counters @ +0..+7*32, master @ +8*32+16, release @ +(16+x)*32
static __device__ __forceinline__ void groupbar(unsigned* bar, int bi, int ni, unsigned e){
  DRAIN_VM();
  __syncthreads();
  if (threadIdx.x == 0){
    unsigned* g = bar + (unsigned)bi * 1024;
    unsigned sub = (unsigned)ni & 7u;
    unsigned old = __hip_atomic_fetch_add(g + sub * 32, 1u, __ATOMIC_RELAXED, __HIP_MEMORY_SCOPE_SYSTEM);
    if (old == 8u * e - 1u){
      unsigned m = __hip_atomic_fetch_add(g + 8 * 32 + 16, 1u, __ATOMIC_RELAXED, __HIP_MEMORY_SCOPE_SYSTEM);
      if (m == 8u * e - 1u){
#pragma unroll
        for (unsigned x = 0; x < 8; ++x) bypass_st4(g + (16u + x) * 32, e);
      }
    }
    const unsigned* rw = g + (16u + sub) * 32;
    while (bypass_ld4_wait(rw) < e) __builtin_amdgcn_s_sleep(2);
  }
  __syncthreads();
}

// ---------------- prep kernels ----------------

__global__ void k_prep_w(const float* __restrict__ Wih, const float* __restrict__ Whh_in,
                         unsigned short* __restrict__ Wx, unsigned short* __restrict__ Whh){
  int jp = blockIdx.x;
  int g = jp & 3, kr = jp >> 2;
  int j = g * NH + kr;
  int k = threadIdx.x * 4;
  float4 a = *(const float4*)(Wih + (size_t)j * (ND + NT) + k);
  float4 b = *(const float4*)(Whh_in + ((size_t)j << 10) + k);
  unsigned short* d1 = Wx + ((size_t)jp << 10) + k;
  unsigned short* d2 = Whh + ((size_t)jp << 10) + k;
  d1[0] = f2bf(a.x); d1[1] = f2bf(a.y); d1[2] = f2bf(a.z); d1[3] = f2bf(a.w);
  d2[0] = f2bf(b.x); d2[1] = f2bf(b.y); d2[2] = f2bf(b.z); d2[3] = f2bf(b.w);
}

__global__ void k_prep_tb(const float* __restrict__ Wih, const float* __restrict__ bih,
                          const float* __restrict__ bhh, float* __restrict__ Wtag,
                          float* __restrict__ biasc){
  int blk = blockIdx.x;
  for (int jp = threadIdx.x; jp < NG; jp += 256){
    int g = jp & 3, kr = jp >> 2;
    int j = g * NH + kr;
    if (blk < NT) Wtag[(size_t)blk * NG + jp] = Wih[(size_t)j * (ND + NT) + ND + blk];
    else          biasc[jp] = bih[j] + bhh[j];
  }
}

__global__ void k_prep_state(float* c, unsigned short* hb0, unsigned short* hb1,
                             float* logits, const float* __restrict__ bout,
                             float* loss, unsigned* bar){
  int i = blockIdx.x * 256 + threadIdx.x;   // grid covers 131072
  c[i] = 0.f; hb0[i] = 0; hb1[i] = 0;
  if (i < 3 * NB * NT) logits[i] = bout[i % NT];
  if (i < 4096) bar[i] = 0;
  if (i == 0) *loss = 0.f;
}

// x[b][s][d] f32 -> xb[(s*128+b)][d] bf16
__global__ void k_xpose(const float* __restrict__ x, unsigned short* __restrict__ xb){
  int r = blockIdx.x;
  int b = r & 127, s = r >> 7;
  int d = threadIdx.x * 4;
  float4 v = *(const float4*)(x + (((size_t)b * NS + s) << 10) + d);
  unsigned short* o = xb + ((size_t)r << 10) + d;
  o[0] = f2bf(v.x); o[1] = f2bf(v.y); o[2] = f2bf(v.z); o[3] = f2bf(v.w);
}

// ---------------- Gx precompute GEMM ----------------
__global__ __launch_bounds__(256, 2) void k_gemm_gx(const unsigned short* __restrict__ xb,
                                                    const unsigned short* __restrict__ Wx,
                                                    unsigned short* __restrict__ Gx, int row0){
  __shared__ unsigned short At[128 * 32];
  __shared__ unsigned short Bt[128 * 32];
  const int tid = threadIdx.x;
  const int wave = tid >> 6, lane = tid & 63;
  const int l15 = lane & 15, l4 = lane >> 4;
  const int wm = wave >> 1, wn = wave & 1;
  const int mloc = (int)blockIdx.x * 128;
  const int n0 = (int)blockIdx.y * 128;
  const unsigned short* Ab = xb + ((size_t)(row0 + mloc) << 10);
  const unsigned short* Bb = Wx + ((size_t)n0 << 10);

  v4f acc[4][4];
#pragma unroll
  for (int i = 0; i < 4; ++i)
#pragma unroll
    for (int j = 0; j < 4; ++j) acc[i][j] = (v4f){0.f, 0.f, 0.f, 0.f};

  for (int kk = 0; kk < 32; ++kk){
    const int k0 = kk * 32;
#pragma unroll
    for (int is = 0; is < 2; ++is){
      int c = is * 256 + tid;
      gload16(Ab + ((size_t)(c >> 2) << 10) + k0 + (c & 3) * 8, At + (is * 256 + wave * 64) * 8);
      gload16(Bb + ((size_t)(c >> 2) << 10) + k0 + (c & 3) * 8, Bt + (is * 256 + wave * 64) * 8);
    }
    __syncthreads();
    v8bf af[4], bfm[4];
#pragma unroll
    for (int i = 0; i < 4; ++i) af[i]  = *(const v8bf*)(At + (wm * 64 + i * 16 + l15) * 32 + l4 * 8);
#pragma unroll
    for (int j = 0; j < 4; ++j) bfm[j] = *(const v8bf*)(Bt + (wn * 64 + j * 16 + l15) * 32 + l4 * 8);
#pragma unroll
    for (int i = 0; i < 4; ++i)
#pragma unroll
      for (int j = 0; j < 4; ++j) acc[i][j] = mfma16x16x32(af[i], bfm[j], acc[i][j]);
    __syncthreads();
  }
#pragma unroll
  for (int i = 0; i < 4; ++i)
#pragma unroll
    for (int j = 0; j < 4; ++j){
      int r = mloc + wm * 64 + i * 16 + l4 * 4;
      int cc = n0 + wn * 64 + j * 16 + l15;
#pragma unroll
      for (int q = 0; q < 4; ++q) Gx[((size_t)(r + q) << 12) + cc] = f2bf(acc[i][j][q]);
    }
}

// ---------------- persistent step kernel ----------------

struct StepArgs {
  const unsigned short* Whh;   // [4096][1024] bf16 permuted (j' = 4k+gate), read from L2
  const unsigned short* Gx;    // [nsteps*128][4096] bf16
  const float* Wtag;           // [20][4096]
  const float* biasc;          // [4096]
  const float* Wout;           // [20][1024] f32
  const float* bout;           // [20]
  const int* tags;             // [128][256]
  const int* mask;             // [128][256]
  unsigned short* hb0;         // [128][1024] bf16 parity buffers (MALL bypass access only)
  unsigned short* hb1;
  float* c;                    // [128][1024] f32 (chunk-boundary spill)
  float* logits;               // [3][128][20] f32 rotating (MALL bypass + atomics)
  float* loss;
  unsigned* bar;
  int s0, nsteps;
};

// 256 wgs (1/CU), 512 threads. wg (bi,ni): 32 batch rows x 64 gate cols, K=1024.
__global__ __launch_bounds__(512, 1) void k_step(StepArgs A){
  __shared__ unsigned short hsl[32 * 1024];   // 64 KB h slab, XOR-swizzled
  __shared__ float sH[32][17];
  __shared__ float sWo[NT][16];
  __shared__ int sPt[32];
  const int tid = threadIdx.x;
  const int wave = tid >> 6, lane = tid & 63;
  const int l15 = lane & 15, l4 = lane >> 4;
  const int wm = wave >> 2, wn = wave & 3;
  const int bi = (int)blockIdx.x >> 6;
  const int ni = (int)blockIdx.x & 63;
  const int b0 = bi * 32;
  const int n0 = ni * 64;

  if (tid < NT * 16){
    int t = tid >> 4, kl = tid & 15;
    sWo[t][kl] = A.Wout[t * NH + (n0 >> 2) + kl];
  }

  const int jl_f = wn * 16 + l15;
  const int jcol = n0 + jl_f;
  const int kh = jcol >> 2;
  const int bb = b0 + wm * 16 + l4 * 4;
  const float gb = A.biasc[jcol];
  const int qb = lane & ~3;
  const int bloc = wm * 16 + l4 * 4;        // b_local base
  const int khl = wn * 4 + (l15 >> 2);      // kh_local (valid on quad-lane-0)

  // A-fragment LDS addressing (m201-style XOR swizzle)
  const char* hbase = (const char*)hsl + ((size_t)(wm * 16 + l15) << 11);
  const unsigned hsw = (unsigned)((l15 & 7) << 4);
  // B operand base in global (L2-resident Whh slice)
  const unsigned short* Bp = A.Whh + ((size_t)jcol << 10) + l4 * 8;

  // staging map: this thread handles row sr, 128B segment sseg
  const int sr = tid & 31;
  const int sseg = tid >> 5;
  char* const sdst = (char*)hsl + ((size_t)sr << 11);
  const unsigned ssw = (unsigned)((sr & 7) << 4);

  float creg[4];
  if ((lane & 3) == 0){
#pragma unroll
    for (int q = 0; q < 4; ++q) creg[q] = A.c[((size_t)(bb + q) << 10) + kh];
  }
  float lacc = 0.f;

  // prefill constant (one dwordx4 of the bout pattern per designated thread)
  v4u myPre = (v4u){0,0,0,0};
  int preRow = -1, preCh = 0;
  if (ni == 32 && tid < 160){
    preRow = tid / 5; preCh = tid - preRow * 5;
    v4f pv = { A.bout[preCh*4+0], A.bout[preCh*4+1], A.bout[preCh*4+2], A.bout[preCh*4+3] };
    myPre = __builtin_bit_cast(v4u, pv);
  }

  // Gx prologue for sl = 0
  float gxv[4];
  {
    const unsigned short* g0 = A.Gx + jcol;
#pragma unroll
    for (int q = 0; q < 4; ++q) gxv[q] = bf2f(g0[(size_t)(bb + q) * NG]);
  }

  __syncthreads();   // sWo ready

  for (int sl = 0; sl < A.nsteps; ++sl){
    const int s = A.s0 + sl;
    const int m  = s % 3;
    const int m1 = (s + 2) % 3;
    const int mz = (s + 1) % 3;
    const unsigned short* hr = (s & 1) ? A.hb1 : A.hb0;
    unsigned short* hw = (s & 1) ? A.hb0 : A.hb1;

    // ---- issue h-slab stage loads (bypass, MALL) ----
    const unsigned short* src = hr + ((size_t)(b0 + sr) << 10) + sseg * 64;
    v4u st[8];
#pragma unroll
    for (int i = 0; i < 8; ++i) st[i] = bypass_ld16(src + i * 8);

    // ---- issue prev-step logits loads (bypass) ----
    v4u aq0, aq1, aq2, aq3, aq4;
    if (tid < 32 && s > 0){
      const float* lr = A.logits + ((size_t)m1 * NB + b0 + tid) * NT;
      aq0 = bypass_ld16(lr + 0);  aq1 = bypass_ld16(lr + 4);
      aq2 = bypass_ld16(lr + 8);  aq3 = bypass_ld16(lr + 12);
      aq4 = bypass_ld16(lr + 16);
    }
    v4u lq0, lq1, lq2, lq3, lq4;
    const int doLoss = (ni == 16 && tid >= 64 && tid < 96 && s > 0);
    if (doLoss){
      const float* lr = A.logits + ((size_t)m1 * NB + b0 + (tid - 64)) * NT;
      lq0 = bypass_ld16(lr + 0);  lq1 = bypass_ld16(lr + 4);
      lq2 = bypass_ld16(lr + 8);  lq3 = bypass_ld16(lr + 12);
      lq4 = bypass_ld16(lr + 16);
    }

    DRAIN_VM();

    // ---- ds_write h slab (swizzled) ----
#pragma unroll
    for (int i = 0; i < 8; ++i)
      *(v4u*)(sdst + (((unsigned)(sseg * 128 + i * 16)) ^ ssw)) = st[i];

    // ---- argmax(prev logits) -> sPt ----
    if (tid < 32){
      int pt = START_IDX_;
      if (s > 0){
        float pv[20];
        *(v4f*)(pv + 0)  = __builtin_bit_cast(v4f, aq0);
        *(v4f*)(pv + 4)  = __builtin_bit_cast(v4f, aq1);
        *(v4f*)(pv + 8)  = __builtin_bit_cast(v4f, aq2);
        *(v4f*)(pv + 12) = __builtin_bit_cast(v4f, aq3);
        *(v4f*)(pv + 16) = __builtin_bit_cast(v4f, aq4);
        float mv = pv[0]; pt = 0;
#pragma unroll
        for (int t = 1; t < NT; ++t){ if (pv[t] > mv){ mv = pv[t]; pt = t; } }
      }
      sPt[tid] = pt;
    }

    // ---- CE loss for step s-1 (designated wg, register-accumulated) ----
    if (doLoss){
      int b = b0 + (tid - 64);
      int tg = A.tags[(size_t)b * NS + (s - 1)];
      int mk = A.mask[(size_t)b * NS + (s - 1)];
      if (mk != 0){
        float pv[20];
        *(v4f*)(pv + 0)  = __builtin_bit_cast(v4f, lq0);
        *(v4f*)(pv + 4)  = __builtin_bit_cast(v4f, lq1);
        *(v4f*)(pv + 8)  = __builtin_bit_cast(v4f, lq2);
        *(v4f*)(pv + 12) = __builtin_bit_cast(v4f, lq3);
        *(v4f*)(pv + 16) = __builtin_bit_cast(v4f, lq4);
        float mv = pv[0];
#pragma unroll
        for (int t = 1; t < NT; ++t) mv = fmaxf(mv, pv[t]);
        float se = 0.f;
#pragma unroll
        for (int t = 0; t < NT; ++t) se += __expf(pv[t] - mv);
        lacc += mv + __logf(se) - pv[tg];
      }
    }

    // ---- pre-fill logits buffer mz with b_out (bypass stores) ----
    if (preRow >= 0)
      bypass_st16(A.logits + ((size_t)mz * NB + b0 + preRow) * NT + preCh * 4, myPre);

    __syncthreads();   // hsl + sPt ready

    // ---- Wtag gather (issue early, hides under GEMM) ----
    float wtv[4];
#pragma unroll
    for (int q = 0; q < 4; ++q)
      wtv[q] = A.Wtag[(size_t)sPt[bloc + q] * NG + jcol];

    // ---- gates GEMM: A from LDS hsl, B from L2 Whh, 2-deep block prefetch ----
    v8bf ba[4], bbx[4];
#pragma unroll
    for (int k = 0; k < 4; ++k) ba[k] = *(const v8bf*)(Bp + k * 32);
    v4f acc = {0.f, 0.f, 0.f, 0.f};
#pragma unroll
    for (int blk = 0; blk < 8; ++blk){
#pragma unroll
      for (int k = 0; k < 4; ++k){
        if (blk < 7){
          v8bf nb = *(const v8bf*)(Bp + ((blk + 1) * 4 + k) * 32);
          if (blk & 1) ba[k] = nb; else bbx[k] = nb;
        }
      }
#pragma unroll
      for (int k = 0; k < 4; ++k){
        const int kk = blk * 4 + k;
        v8bf a = *(const v8bf*)(hbase + (((unsigned)(kk * 64 + l4 * 16)) ^ hsw));
        acc = mfma16x16x32(a, (blk & 1) ? bbx[k] : ba[k], acc);
      }
    }

    float gv[4];
#pragma unroll
    for (int q = 0; q < 4; ++q)
      gv[q] = acc[q] + gb + gxv[q] + wtv[q];

#pragma unroll
    for (int q = 0; q < 4; ++q){
      float iv = __shfl(gv[q], qb + 0);
      float fv = __shfl(gv[q], qb + 1);
      float gg = __shfl(gv[q], qb + 2);
      float ov = __shfl(gv[q], qb + 3);
      if ((lane & 3) == 0){
        float cn = sigm(fv) * creg[q] + sigm(iv) * tanhf_(gg);
        float hn = sigm(ov) * tanhf_(cn);
        creg[q] = cn;
        bypass_st2(hw + ((size_t)(bb + q) << 10) + kh, (unsigned)f2bf(hn));
        sH[bloc + q][khl] = hn;
      }
    }
    __syncthreads();   // sH complete

    // ---- logits partials: 640 (t,b) pairs, dot over this wg's 16 k's ----
    for (int idx = tid; idx < 32 * NT; idx += 512){
      int t = idx >> 5, b = idx & 31;
      float p = 0.f;
#pragma unroll
      for (int k = 0; k < 16; ++k) p += sH[b][k] * sWo[t][k];
      atomicAdd(A.logits + ((size_t)m * NB + b0 + b) * NT + t, p);
    }

    // ---- Gx prefetch for next step (normal cached loads) ----
    float gxn[4] = {0.f, 0.f, 0.f, 0.f};
    if (sl + 1 < A.nsteps){
      const unsigned short* gn = A.Gx + (size_t)(sl + 1) * NB * NG + jcol;
#pragma unroll
      for (int q = 0; q < 4; ++q) gxn[q] = bf2f(gn[(size_t)(bb + q) * NG]);
    }

    groupbar(A.bar, bi, ni, (unsigned)(s + 1));

#pragma unroll
    for (int q = 0; q < 4; ++q) gxv[q] = gxn[q];
  }

  // epilogue: spill c for chunk boundary, flush loss once
  if ((lane & 3) == 0){
#pragma unroll
    for (int q = 0; q < 4; ++q) A.c[((size_t)(bb + q) << 10) + kh] = creg[q];
  }
  if (ni == 16 && tid >= 64 && tid < 96) atomicAdd(A.loss, lacc);
}

// final: loss for last step + total
__global__ void k_final(const float* __restrict__ logits, const int* __restrict__ tags,
                        const int* __restrict__ mask, const float* __restrict__ loss,
                        float* __restrict__ out){
  __shared__ float red[NB];
  int b = threadIdx.x;
  const int s = NS - 1;
  const float* lr = logits + ((size_t)(s % 3) * NB + b) * NT;
  float v = 0.f;
  int tg = tags[(size_t)b * NS + s];
  int mk = mask[(size_t)b * NS + s];
  if (mk != 0){
    float mv = lr[0];
    for (int t = 1; t < NT; ++t) mv = fmaxf(mv, lr[t]);
    float se = 0.f;
    for (int t = 0; t < NT; ++t) se += __expf(lr[t] - mv);
    v = mv + __logf(se) - lr[tg];
  }
  red[b] = v;
  __syncthreads();
  if (b == 0){
    float tot = *loss;
    for (int i = 0; i < NB; ++i) tot += red[i];
    out[0] = tot;
  }
}

// ---------------- host ----------------

extern "C" void kernel_launch(void* const* d_in, const int* in_sizes, int n_in,
                              void* d_out, int out_size, void* d_ws, size_t ws_size,
                              hipStream_t stream){
  const float* x      = (const float*)d_in[0];
  const int*   tags   = (const int*)  d_in[1];
  const int*   mask   = (const int*)  d_in[2];
  const float* Wih    = (const float*)d_in[3];
  const float* Whh_in = (const float*)d_in[4];
  const float* bih    = (const float*)d_in[5];
  const float* bhh    = (const float*)d_in[6];
  const float* Wout   = (const float*)d_in[7];
  const float* bout   = (const float*)d_in[8];

  char* base = (char*)d_ws;
  size_t off = 0;
  auto alloc = [&](size_t bytes) -> char* {
    char* p = base + off;
    off = (off + bytes + 255) & ~(size_t)255;
    return p;
  };
  unsigned short* Wx    = (unsigned short*)alloc((size_t)NG * NH * 2);
  unsigned short* Whh   = (unsigned short*)alloc((size_t)NG * NH * 2);
  float*          Wtag  = (float*)alloc((size_t)NT * NG * 4);
  float*          biasc = (float*)alloc((size_t)NG * 4);
  unsigned short* hb0   = (unsigned short*)alloc((size_t)NB * NH * 2);
  unsigned short* hb1   = (unsigned short*)alloc((size_t)NB * NH * 2);
  float*          c     = (float*)alloc((size_t)NB * NH * 4);
  float*          logits= (float*)alloc((size_t)3 * NB * NT * 4);
  float*          loss  = (float*)alloc(256);
  unsigned*       bar   = (unsigned*)alloc(16384);
  unsigned short* xb    = (unsigned short*)alloc((size_t)NS * NB * NH * 2);

  size_t fixed = off;
  int schunk = NS;
  while (schunk > 1 && fixed + (size_t)schunk * NB * NG * 2 > ws_size) schunk >>= 1;
  unsigned short* Gx = (unsigned short*)alloc((size_t)schunk * NB * NG * 2);

  k_prep_w<<<NG, 256, 0, stream>>>(Wih, Whh_in, Wx, Whh);
  k_prep_tb<<<NT + 1, 256, 0, stream>>>(Wih, bih, bhh, Wtag, biasc);
  k_prep_state<<<(NB * NH) / 256, 256, 0, stream>>>(c, hb0, hb1, logits, bout, loss, bar);
  k_xpose<<<NS * NB, 256, 0, stream>>>(x, xb);

  int done = 0;
  while (done < NS){
    int ns = (NS - done < schunk) ? (NS - done) : schunk;
    k_gemm_gx<<<dim3(ns, 32), 256, 0, stream>>>(xb, Wx, Gx, done * NB);
    StepArgs sa;
    sa.Whh = Whh; sa.Gx = Gx; sa.Wtag = Wtag; sa.biasc = biasc;
    sa.Wout = Wout; sa.bout = bout; sa.tags = tags; sa.mask = mask;
    sa.hb0 = hb0; sa.hb1 = hb1; sa.c = c; sa.logits = logits;
    sa.loss = loss; sa.bar = bar; sa.s0 = done; sa.nsteps = ns;
    void* kargs[] = { &sa };
    hipLaunchKernelGGL(k_step, dim3(NBLK), dim3(512), 0, stream, sa);
    done += ns;
  }
  k_final<<<1, NB, 0, stream>>>(logits, tags, mask, loss, (float*)d_out);
}

// Round 4
// 4632.925 us; speedup vs baseline: 1.7661x; 1.7661x over previous
//
#include <hip/hip_runtime.h>

#define NB 128
#define NS 256
#define ND 1024
#define NH 1024
#define NT 20
#define NG 4096
#define START_IDX_ 19
#define NBLK 256u

typedef __bf16 v8bf __attribute__((ext_vector_type(8)));
typedef float v4f __attribute__((ext_vector_type(4)));
typedef unsigned int v4u __attribute__((ext_vector_type(4)));
typedef unsigned int v2u __attribute__((ext_vector_type(2)));
typedef unsigned short v8us __attribute__((ext_vector_type(8)));

static __device__ __forceinline__ unsigned short f2bf(float f){
  union { float f; unsigned u; } v; v.f = f;
  unsigned r = v.u + 0x7fffu + ((v.u >> 16) & 1u);
  return (unsigned short)(r >> 16);
}
static __device__ __forceinline__ float bf2f(unsigned short h){
  union { unsigned u; float f; } v; v.u = ((unsigned)h) << 16; return v.f;
}
static __device__ __forceinline__ float sigm(float x){ return 1.0f / (1.0f + __expf(-x)); }
static __device__ __forceinline__ float tanhf_(float x){ return 1.0f - 2.0f / (__expf(2.0f * x) + 1.0f); }

typedef __attribute__((address_space(1))) const unsigned int gu32_t;
typedef __attribute__((address_space(3))) unsigned int lu32_t;
static __device__ __forceinline__ void gload16(const void* g, void* l){
  __builtin_amdgcn_global_load_lds((gu32_t*)g, (lu32_t*)l, 16, 0, 0);
}
static __device__ __forceinline__ v4f mfma16x16x32(v8bf a, v8bf b, v4f c){
  return __builtin_amdgcn_mfma_f32_16x16x32_bf16(a, b, c, 0, 0, 0);
}

// ---- MALL-coherent (L0+L2 bypass) access helpers ----
static __device__ __forceinline__ v4u bypass_ld16(const void* p){
  v4u r; asm volatile("global_load_dwordx4 %0, %1, off sc0 sc1" : "=v"(r) : "v"(p)); return r;
}
static __device__ __forceinline__ void bypass_st8(void* p, v2u v){
  asm volatile("global_store_dwordx2 %0, %1, off sc0 sc1" :: "v"(p), "v"(v) : "memory");
}
static __device__ __forceinline__ void bypass_st4(void* p, unsigned v){
  asm volatile("global_store_dword %0, %1, off sc0 sc1" :: "v"(p), "v"(v) : "memory");
}
static __device__ __forceinline__ unsigned bypass_ld4_wait(const void* p){
  unsigned r;
  asm volatile("global_load_dword %0, %1, off sc0 sc1\n\ts_waitcnt vmcnt(0)"
               : "=v"(r) : "v"(p) : "memory");
  return r;
}
#define DRAIN_VM() { asm volatile("s_waitcnt vmcnt(0)" ::: "memory"); __builtin_amdgcn_sched_barrier(0); }

static __device__ __forceinline__ unsigned atom_add_sys(unsigned* p, unsigned v){
  return __hip_atomic_fetch_add(p, v, __ATOMIC_RELAXED, __HIP_MEMORY_SCOPE_SYSTEM);
}

// ---- channel-spread hierarchical per-batch-group barrier ----
// u32 word index stride 2048 (=8KB) between ALL hot words:
//   arrival[bi][sub] @ (bi*8+sub)*2048      (8 arrivals each, sub = ni&7)
//   mid[bi]          @ (32+bi)*2048         (8 arrivals)
//   release[bi][sub] @ (64+bi*8+sub)*2048   (8 pollers each)
static __device__ __forceinline__ void groupbar(unsigned* bar, int bi, int ni, unsigned e){
  DRAIN_VM();
  __syncthreads();
  if (threadIdx.x == 0){
    unsigned sub = (unsigned)ni & 7u;
    unsigned old = atom_add_sys(bar + ((unsigned)bi * 8u + sub) * 2048u, 1u);
    if (old == 8u * e - 1u){
      unsigned m = atom_add_sys(bar + (32u + (unsigned)bi) * 2048u, 1u);
      if (m == 8u * e - 1u){
#pragma unroll
        for (unsigned x = 0; x < 8; ++x)
          bypass_st4(bar + (64u + (unsigned)bi * 8u + x) * 2048u, e);
      }
    }
    const unsigned* rw = bar + (64u + (unsigned)bi * 8u + sub) * 2048u;
    while (bypass_ld4_wait(rw) < e) __builtin_amdgcn_s_sleep(1);
  }
  __syncthreads();
}

// ---------------- prep kernels ----------------

__global__ void k_prep_w(const float* __restrict__ Wih, const float* __restrict__ Whh_in,
                         unsigned short* __restrict__ Wx, unsigned short* __restrict__ Whh){
  int jp = blockIdx.x;
  int g = jp & 3, kr = jp >> 2;
  int j = g * NH + kr;
  int k = threadIdx.x * 4;
  float4 a = *(const float4*)(Wih + (size_t)j * (ND + NT) + k);
  float4 b = *(const float4*)(Whh_in + ((size_t)j << 10) + k);
  unsigned short* d1 = Wx + ((size_t)jp << 10) + k;
  unsigned short* d2 = Whh + ((size_t)jp << 10) + k;
  d1[0] = f2bf(a.x); d1[1] = f2bf(a.y); d1[2] = f2bf(a.z); d1[3] = f2bf(a.w);
  d2[0] = f2bf(b.x); d2[1] = f2bf(b.y); d2[2] = f2bf(b.z); d2[3] = f2bf(b.w);
}

__global__ void k_prep_tb(const float* __restrict__ Wih, const float* __restrict__ bih,
                          const float* __restrict__ bhh, float* __restrict__ Wtag,
                          float* __restrict__ biasc){
  int blk = blockIdx.x;
  for (int jp = threadIdx.x; jp < NG; jp += 256){
    int g = jp & 3, kr = jp >> 2;
    int j = g * NH + kr;
    if (blk < NT) Wtag[(size_t)blk * NG + jp] = Wih[(size_t)j * (ND + NT) + ND + blk];
    else          biasc[jp] = bih[j] + bhh[j];
  }
}

__global__ void k_prep_state(float* c, unsigned short* hb0, unsigned short* hb1,
                             float* loss, unsigned* bar){
  int i = blockIdx.x * 256 + threadIdx.x;   // grid covers 131072
  c[i] = 0.f; hb0[i] = 0; hb1[i] = 0;
  if (i < 96) bar[(size_t)i * 2048] = 0;
  if (i == 0) *loss = 0.f;
}

// x[b][s][d] f32 -> xb[(s*128+b)][d] bf16
__global__ void k_xpose(const float* __restrict__ x, unsigned short* __restrict__ xb){
  int r = blockIdx.x;
  int b = r & 127, s = r >> 7;
  int d = threadIdx.x * 4;
  float4 v = *(const float4*)(x + (((size_t)b * NS + s) << 10) + d);
  unsigned short* o = xb + ((size_t)r << 10) + d;
  o[0] = f2bf(v.x); o[1] = f2bf(v.y); o[2] = f2bf(v.z); o[3] = f2bf(v.w);
}

// ---------------- Gx precompute GEMM ----------------
__global__ __launch_bounds__(256, 2) void k_gemm_gx(const unsigned short* __restrict__ xb,
                                                    const unsigned short* __restrict__ Wx,
                                                    unsigned short* __restrict__ Gx, int row0){
  __shared__ unsigned short At[128 * 32];
  __shared__ unsigned short Bt[128 * 32];
  const int tid = threadIdx.x;
  const int wave = tid >> 6, lane = tid & 63;
  const int l15 = lane & 15, l4 = lane >> 4;
  const int wm = wave >> 1, wn = wave & 1;
  const int mloc = (int)blockIdx.x * 128;
  const int n0 = (int)blockIdx.y * 128;
  const unsigned short* Ab = xb + ((size_t)(row0 + mloc) << 10);
  const unsigned short* Bb = Wx + ((size_t)n0 << 10);

  v4f acc[4][4];
#pragma unroll
  for (int i = 0; i < 4; ++i)
#pragma unroll
    for (int j = 0; j < 4; ++j) acc[i][j] = (v4f){0.f, 0.f, 0.f, 0.f};

  for (int kk = 0; kk < 32; ++kk){
    const int k0 = kk * 32;
#pragma unroll
    for (int is = 0; is < 2; ++is){
      int c = is * 256 + tid;
      gload16(Ab + ((size_t)(c >> 2) << 10) + k0 + (c & 3) * 8, At + (is * 256 + wave * 64) * 8);
      gload16(Bb + ((size_t)(c >> 2) << 10) + k0 + (c & 3) * 8, Bt + (is * 256 + wave * 64) * 8);
    }
    __syncthreads();
    v8bf af[4], bfm[4];
#pragma unroll
    for (int i = 0; i < 4; ++i) af[i]  = *(const v8bf*)(At + (wm * 64 + i * 16 + l15) * 32 + l4 * 8);
#pragma unroll
    for (int j = 0; j < 4; ++j) bfm[j] = *(const v8bf*)(Bt + (wn * 64 + j * 16 + l15) * 32 + l4 * 8);
#pragma unroll
    for (int i = 0; i < 4; ++i)
#pragma unroll
      for (int j = 0; j < 4; ++j) acc[i][j] = mfma16x16x32(af[i], bfm[j], acc[i][j]);
    __syncthreads();
  }
#pragma unroll
  for (int i = 0; i < 4; ++i)
#pragma unroll
    for (int j = 0; j < 4; ++j){
      int r = mloc + wm * 64 + i * 16 + l4 * 4;
      int cc = n0 + wn * 64 + j * 16 + l15;
#pragma unroll
      for (int q = 0; q < 4; ++q) Gx[((size_t)(r + q) << 12) + cc] = f2bf(acc[i][j][q]);
    }
}

// ---------------- persistent step kernel ----------------

struct StepArgs {
  const unsigned short* Whh;   // [4096][1024] bf16 permuted (j' = 4k+gate), L2-read
  const unsigned short* Gx;    // [nsteps*128][4096] bf16
  const float* Wtag;           // [20][4096]
  const float* biasc;          // [4096]
  const float* Wout;           // [20][1024] f32
  const float* bout;           // [20]
  const int* tags;             // [128][256]
  const int* mask;             // [128][256]
  unsigned short* hb0;         // [128][1024] bf16 parity buffers (MALL bypass)
  unsigned short* hb1;
  float* c;                    // [128][1024] f32 (chunk-boundary spill)
  float* loss;
  unsigned* bar;
  int s0, nsteps;
};

// 256 wgs (1/CU), 512 threads. wg (bi,ni): 32 batch rows x 64 gate cols, K=1024.
__global__ __launch_bounds__(512, 1) void k_step(StepArgs A){
  __shared__ unsigned short hsl[32 * 1024];   // 64 KB h slab (XOR-swizzled)
  __shared__ float sred[8 * 32 * 33];         // 33 KB logits k-split partials
  __shared__ float sLog[32 * 21];             // summed logits
  __shared__ unsigned short sHW[32 * 16];     // h-out coalescing tile
  __shared__ int sPt[32];
  __shared__ float sBo[NT];
  const int tid = threadIdx.x;
  const int wave = tid >> 6, lane = tid & 63;
  const int l15 = lane & 15, l4 = lane >> 4;
  const int wm = wave >> 2, wn = wave & 3;
  const int bi = (int)blockIdx.x >> 6;
  const int ni = (int)blockIdx.x & 63;
  const int b0 = bi * 32;
  const int n0 = ni * 64;

  if (tid < NT) sBo[tid] = A.bout[tid];

  const int jl_f = wn * 16 + l15;
  const int jcol = n0 + jl_f;
  const int kh = jcol >> 2;
  const int bb = b0 + wm * 16 + l4 * 4;
  const float gb = A.biasc[jcol];
  const int qb = lane & ~3;
  const int bloc = wm * 16 + l4 * 4;        // b_local base
  const int khl = wn * 4 + (l15 >> 2);      // kh_local (valid on quad-lane-0)

  // gates A-fragment LDS addressing
  const char* hbase = (const char*)hsl + ((size_t)(wm * 16 + l15) << 11);
  const unsigned hsw = (unsigned)((l15 & 7) << 4);
  // gates B operand base (L2-resident Whh slice)
  const unsigned short* Bp = A.Whh + ((size_t)jcol << 10) + l4 * 8;

  // staging map: thread handles row sr, 128B segment sseg
  const int sr = tid & 31;
  const int sseg = tid >> 5;
  char* const sdst = (char*)hsl + ((size_t)sr << 11);
  const unsigned ssw = (unsigned)((sr & 7) << 4);

  // logits Wout B-fragments in registers (bf16), k-split: wave handles kk = wave*4..+4
  v8bf wfr0[4], wfr1[4];
  {
    const int kb = wave * 128 + l4 * 8;
#pragma unroll
    for (int nj = 0; nj < 2; ++nj){
      int t = nj * 16 + l15;
#pragma unroll
      for (int kkl = 0; kkl < 4; ++kkl){
        v8us uu = (v8us){0,0,0,0,0,0,0,0};
        if (t < NT){
          const float* wp = A.Wout + (size_t)t * NH + kb + kkl * 32;
          float4 w0 = *(const float4*)wp;
          float4 w1 = *(const float4*)(wp + 4);
          uu[0]=f2bf(w0.x); uu[1]=f2bf(w0.y); uu[2]=f2bf(w0.z); uu[3]=f2bf(w0.w);
          uu[4]=f2bf(w1.x); uu[5]=f2bf(w1.y); uu[6]=f2bf(w1.z); uu[7]=f2bf(w1.w);
        }
        v8bf w = __builtin_bit_cast(v8bf, uu);
        if (nj == 0) wfr0[kkl] = w; else wfr1[kkl] = w;
      }
    }
  }

  float creg[4];
  if ((lane & 3) == 0){
#pragma unroll
    for (int q = 0; q < 4; ++q) creg[q] = A.c[((size_t)(bb + q) << 10) + kh];
  }
  float lacc = 0.f;

  // Gx prologue for sl = 0
  float gxv[4];
  {
    const unsigned short* g0 = A.Gx + jcol;
#pragma unroll
    for (int q = 0; q < 4; ++q) gxv[q] = bf2f(g0[(size_t)(bb + q) * NG]);
  }

  __syncthreads();   // sBo ready

  for (int sl = 0; sl < A.nsteps; ++sl){
    const int s = A.s0 + sl;
    const unsigned short* hr = (s & 1) ? A.hb1 : A.hb0;
    unsigned short* hw = (s & 1) ? A.hb0 : A.hb1;

    // ---- issue h-slab stage loads (bypass, MALL) + first gates-B block ----
    const unsigned short* src = hr + ((size_t)(b0 + sr) << 10) + sseg * 64;
    v4u st[8];
#pragma unroll
    for (int i = 0; i < 8; ++i) st[i] = bypass_ld16(src + i * 8);
    v8bf ba[4], bbx[4];
#pragma unroll
    for (int k = 0; k < 4; ++k) ba[k] = *(const v8bf*)(Bp + k * 32);

    DRAIN_VM();

    // ---- ds_write h slab (swizzled) ----
#pragma unroll
    for (int i = 0; i < 8; ++i)
      *(v4u*)(sdst + (((unsigned)(sseg * 128 + i * 16)) ^ ssw)) = st[i];
    __syncthreads();   // hsl = h(s-1) ready

    // ---- local logits(s-1) via MFMA: D[b][t] = h @ Wout^T, k-split over waves ----
    v4f d00 = (v4f){0,0,0,0}, d01 = (v4f){0,0,0,0};
    v4f d10 = (v4f){0,0,0,0}, d11 = (v4f){0,0,0,0};
#pragma unroll
    for (int kkl = 0; kkl < 4; ++kkl){
      const unsigned ko = (unsigned)((wave * 4 + kkl) * 64 + l4 * 16);
      v8bf a0 = *(const v8bf*)((const char*)hsl + ((size_t)l15 << 11) + (ko ^ ((l15 & 7) << 4)));
      v8bf a1 = *(const v8bf*)((const char*)hsl + ((size_t)(16 + l15) << 11) + (ko ^ ((l15 & 7) << 4)));
      d00 = mfma16x16x32(a0, wfr0[kkl], d00);
      d10 = mfma16x16x32(a1, wfr0[kkl], d10);
      d01 = mfma16x16x32(a0, wfr1[kkl], d01);
      d11 = mfma16x16x32(a1, wfr1[kkl], d11);
    }
    {
      float* rp = sred + (size_t)wave * 32 * 33;
      const int rb = l4 * 4;
#pragma unroll
      for (int q = 0; q < 4; ++q){
        rp[(rb + q) * 33 + l15]           = d00[q];
        rp[(rb + q) * 33 + 16 + l15]      = d01[q];
        rp[(16 + rb + q) * 33 + l15]      = d10[q];
        rp[(16 + rb + q) * 33 + 16 + l15] = d11[q];
      }
    }
    __syncthreads();   // sred ready

    // ---- k-reduce + bias -> sLog ----
    for (int idx = tid; idx < 32 * NT; idx += 512){
      int b = idx / NT, t = idx - b * NT;
      float v = sBo[t];
#pragma unroll
      for (int w8 = 0; w8 < 8; ++w8) v += sred[(size_t)w8 * 32 * 33 + b * 33 + t];
      sLog[b * 21 + t] = v;
    }
    __syncthreads();   // sLog ready

    // ---- argmax -> sPt; CE loss(s-1) by designated wg ----
    if (tid < 32){
      int pt = START_IDX_;
      if (s > 0){
        const float* lr = sLog + tid * 21;
        float mv = lr[0]; pt = 0;
#pragma unroll
        for (int t = 1; t < NT; ++t){ float v = lr[t]; if (v > mv){ mv = v; pt = t; } }
      }
      sPt[tid] = pt;
    }
    if (ni == 16 && tid >= 64 && tid < 96 && s > 0){
      int bl = tid - 64;
      int b = b0 + bl;
      int tg = A.tags[(size_t)b * NS + (s - 1)];
      int mk = A.mask[(size_t)b * NS + (s - 1)];
      if (mk != 0){
        const float* lr = sLog + bl * 21;
        float mv = lr[0];
#pragma unroll
        for (int t = 1; t < NT; ++t) mv = fmaxf(mv, lr[t]);
        float se = 0.f;
#pragma unroll
        for (int t = 0; t < NT; ++t) se += __expf(lr[t] - mv);
        lacc += mv + __logf(se) - lr[tg];
      }
    }
    __syncthreads();   // sPt ready

    // ---- Wtag gather (overlaps GEMM) ----
    float wtv[4];
#pragma unroll
    for (int q = 0; q < 4; ++q)
      wtv[q] = A.Wtag[(size_t)sPt[bloc + q] * NG + jcol];

    // ---- gates GEMM: A from hsl, B from L2 Whh, 2-deep block prefetch ----
    v4f acc = (v4f){0,0,0,0};
#pragma unroll
    for (int blk = 0; blk < 8; ++blk){
#pragma unroll
      for (int k = 0; k < 4; ++k){
        if (blk < 7){
          v8bf nb = *(const v8bf*)(Bp + ((blk + 1) * 4 + k) * 32);
          if (blk & 1) ba[k] = nb; else bbx[k] = nb;
        }
      }
#pragma unroll
      for (int k = 0; k < 4; ++k){
        const int kk = blk * 4 + k;
        v8bf a = *(const v8bf*)(hbase + (((unsigned)(kk * 64 + l4 * 16)) ^ hsw));
        acc = mfma16x16x32(a, (blk & 1) ? bbx[k] : ba[k], acc);
      }
    }

    float gv[4];
#pragma unroll
    for (int q = 0; q < 4; ++q)
      gv[q] = acc[q] + gb + gxv[q] + wtv[q];

#pragma unroll
    for (int q = 0; q < 4; ++q){
      float iv = __shfl(gv[q], qb + 0);
      float fv = __shfl(gv[q], qb + 1);
      float gg = __shfl(gv[q], qb + 2);
      float ov = __shfl(gv[q], qb + 3);
      if ((lane & 3) == 0){
        float cn = sigm(fv) * creg[q] + sigm(iv) * tanhf_(gg);
        float hn = sigm(ov) * tanhf_(cn);
        creg[q] = cn;
        sHW[(bloc + q) * 16 + khl] = f2bf(hn);
      }
    }

    // ---- Gx prefetch for next step ----
    float gxn[4] = {0.f, 0.f, 0.f, 0.f};
    if (sl + 1 < A.nsteps){
      const unsigned short* gn = A.Gx + (size_t)(sl + 1) * NB * NG + jcol;
#pragma unroll
      for (int q = 0; q < 4; ++q) gxn[q] = bf2f(gn[(size_t)(bb + q) * NG]);
    }
    __syncthreads();   // sHW ready

    // ---- coalesced h store: 128 threads x 8B (wg owns 16 consecutive k-units) ----
    if (tid < 128){
      int r = tid >> 2, seg = tid & 3;
      unsigned long long uv = *(const unsigned long long*)(sHW + r * 16 + seg * 4);
      bypass_st8(hw + ((size_t)(b0 + r) << 10) + (n0 >> 2) + seg * 4,
                 __builtin_bit_cast(v2u, uv));
    }

    groupbar(A.bar, bi, ni, (unsigned)(s + 1));

#pragma unroll
    for (int q = 0; q < 4; ++q) gxv[q] = gxn[q];
  }

  // epilogue: spill c for chunk boundary, flush loss once
  if ((lane & 3) == 0){
#pragma unroll
    for (int q = 0; q < 4; ++q) A.c[((size_t)(bb + q) << 10) + kh] = creg[q];
  }
  if (ni == 16 && tid >= 64 && tid < 96) atomicAdd(A.loss, lacc);
}

// final: logits + CE for step NS-1 (h(NS-1) lives in hb0), plus accumulated loss
__global__ __launch_bounds__(1024) void k_final(const unsigned short* __restrict__ hlast,
                        const float* __restrict__ Wout, const float* __restrict__ bout,
                        const int* __restrict__ tags, const int* __restrict__ mask,
                        const float* __restrict__ loss, float* __restrict__ out){
  __shared__ float fl[NB * NT];
  __shared__ float red[NB];
  const int tid = threadIdx.x;
  for (int idx = tid; idx < NB * NT; idx += 1024){
    int b = idx / NT, t = idx - b * NT;
    const unsigned short* hp = hlast + ((size_t)b << 10);
    const float* wp = Wout + (size_t)t * NH;
    float acc = 0.f;
    for (int k = 0; k < NH; k += 8){
      ushort4 h0 = *(const ushort4*)(hp + k);
      ushort4 h1 = *(const ushort4*)(hp + k + 4);
      float4 w0 = *(const float4*)(wp + k);
      float4 w1 = *(const float4*)(wp + k + 4);
      acc += bf2f(h0.x)*w0.x + bf2f(h0.y)*w0.y + bf2f(h0.z)*w0.z + bf2f(h0.w)*w0.w
           + bf2f(h1.x)*w1.x + bf2f(h1.y)*w1.y + bf2f(h1.z)*w1.z + bf2f(h1.w)*w1.w;
    }
    fl[idx] = acc + bout[t];
  }
  __syncthreads();
  if (tid < NB){
    const float* lr = fl + tid * NT;
    int tg = tags[(size_t)tid * NS + (NS - 1)];
    int mk = mask[(size_t)tid * NS + (NS - 1)];
    float v = 0.f;
    if (mk != 0){
      float mv = lr[0];
      for (int t = 1; t < NT; ++t) mv = fmaxf(mv, lr[t]);
      float se = 0.f;
      for (int t = 0; t < NT; ++t) se += __expf(lr[t] - mv);
      v = mv + __logf(se) - lr[tg];
    }
    red[tid] = v;
  }
  __syncthreads();
  if (tid == 0){
    float tot = *loss;
    for (int i = 0; i < NB; ++i) tot += red[i];
    out[0] = tot;
  }
}

// ---------------- host ----------------

extern "C" void kernel_launch(void* const* d_in, const int* in_sizes, int n_in,
                              void* d_out, int out_size, void* d_ws, size_t ws_size,
                              hipStream_t stream){
  const float* x      = (const float*)d_in[0];
  const int*   tags   = (const int*)  d_in[1];
  const int*   mask   = (const int*)  d_in[2];
  const float* Wih    = (const float*)d_in[3];
  const float* Whh_in = (const float*)d_in[4];
  const float* bih    = (const float*)d_in[5];
  const float* bhh    = (const float*)d_in[6];
  const float* Wout   = (const float*)d_in[7];
  const float* bout   = (const float*)d_in[8];

  char* base = (char*)d_ws;
  size_t off = 0;
  auto alloc = [&](size_t bytes) -> char* {
    char* p = base + off;
    off = (off + bytes + 255) & ~(size_t)255;
    return p;
  };
  unsigned short* Wx    = (unsigned short*)alloc((size_t)NG * NH * 2);
  unsigned short* Whh   = (unsigned short*)alloc((size_t)NG * NH * 2);
  float*          Wtag  = (float*)alloc((size_t)NT * NG * 4);
  float*          biasc = (float*)alloc((size_t)NG * 4);
  unsigned short* hb0   = (unsigned short*)alloc((size_t)NB * NH * 2);
  unsigned short* hb1   = (unsigned short*)alloc((size_t)NB * NH * 2);
  float*          c     = (float*)alloc((size_t)NB * NH * 4);
  float*          loss  = (float*)alloc(256);
  unsigned*       bar   = (unsigned*)alloc((size_t)96 * 8192 + 256);
  unsigned short* xb    = (unsigned short*)alloc((size_t)NS * NB * NH * 2);

  size_t fixed = off;
  int schunk = NS;
  while (schunk > 1 && fixed + (size_t)schunk * NB * NG * 2 > ws_size) schunk >>= 1;
  unsigned short* Gx = (unsigned short*)alloc((size_t)schunk * NB * NG * 2);

  k_prep_w<<<NG, 256, 0, stream>>>(Wih, Whh_in, Wx, Whh);
  k_prep_tb<<<NT + 1, 256, 0, stream>>>(Wih, bih, bhh, Wtag, biasc);
  k_prep_state<<<(NB * NH) / 256, 256, 0, stream>>>(c, hb0, hb1, loss, bar);
  k_xpose<<<NS * NB, 256, 0, stream>>>(x, xb);

  int done = 0;
  while (done < NS){
    int ns = (NS - done < schunk) ? (NS - done) : schunk;
    k_gemm_gx<<<dim3(ns, 32), 256, 0, stream>>>(xb, Wx, Gx, done * NB);
    StepArgs sa;
    sa.Whh = Whh; sa.Gx = Gx; sa.Wtag = Wtag; sa.biasc = biasc;
    sa.Wout = Wout; sa.bout = bout; sa.tags = tags; sa.mask = mask;
    sa.hb0 = hb0; sa.hb1 = hb1; sa.c = c;
    sa.loss = loss; sa.bar = bar; sa.s0 = done; sa.nsteps = ns;
    hipLaunchKernelGGL(k_step, dim3(NBLK), dim3(512), 0, stream, sa);
    done += ns;
  }
  k_final<<<1, 1024, 0, stream>>>(hb0, Wout, bout, tags, mask, loss, (float*)d_out);
}

// Round 5
// 3557.594 us; speedup vs baseline: 2.2999x; 1.3023x over previous
//
#include <hip/hip_runtime.h>

#define NB 128
#define NS 256
#define ND 1024
#define NH 1024
#define NT 20
#define NG 4096
#define START_IDX_ 19
#define NBLK 256u

typedef __bf16 v8bf __attribute__((ext_vector_type(8)));
typedef float v4f __attribute__((ext_vector_type(4)));
typedef unsigned int v4u __attribute__((ext_vector_type(4)));
typedef unsigned int v2u __attribute__((ext_vector_type(2)));
typedef unsigned short v8us __attribute__((ext_vector_type(8)));

static __device__ __forceinline__ unsigned short f2bf(float f){
  union { float f; unsigned u; } v; v.f = f;
  unsigned r = v.u + 0x7fffu + ((v.u >> 16) & 1u);
  return (unsigned short)(r >> 16);
}
static __device__ __forceinline__ float bf2f(unsigned short h){
  union { unsigned u; float f; } v; v.u = ((unsigned)h) << 16; return v.f;
}
static __device__ __forceinline__ float sigm(float x){ return 1.0f / (1.0f + __expf(-x)); }
static __device__ __forceinline__ float tanhf_(float x){ return 1.0f - 2.0f / (__expf(2.0f * x) + 1.0f); }

typedef __attribute__((address_space(1))) const unsigned int gu32_t;
typedef __attribute__((address_space(3))) unsigned int lu32_t;
static __device__ __forceinline__ void gload16(const void* g, void* l){
  __builtin_amdgcn_global_load_lds((gu32_t*)g, (lu32_t*)l, 16, 0, 0);
}
static __device__ __forceinline__ v4f mfma16x16x32(v8bf a, v8bf b, v4f c){
  return __builtin_amdgcn_mfma_f32_16x16x32_bf16(a, b, c, 0, 0, 0);
}

// ---- MALL-coherent (L0+L2 bypass) access helpers ----
static __device__ __forceinline__ v4u bypass_ld16(const void* p){
  v4u r; asm volatile("global_load_dwordx4 %0, %1, off sc0 sc1" : "=v"(r) : "v"(p)); return r;
}
static __device__ __forceinline__ void bypass_st8(void* p, v2u v){
  asm volatile("global_store_dwordx2 %0, %1, off sc0 sc1" :: "v"(p), "v"(v) : "memory");
}
static __device__ __forceinline__ void bypass_st4(void* p, unsigned v){
  asm volatile("global_store_dword %0, %1, off sc0 sc1" :: "v"(p), "v"(v) : "memory");
}
static __device__ __forceinline__ unsigned bypass_ld4_wait(const void* p){
  unsigned r;
  asm volatile("global_load_dword %0, %1, off sc0 sc1\n\ts_waitcnt vmcnt(0)"
               : "=v"(r) : "v"(p) : "memory");
  return r;
}
#define DRAIN_VM() { asm volatile("s_waitcnt vmcnt(0)" ::: "memory"); __builtin_amdgcn_sched_barrier(0); }

// ---------------- prep kernels ----------------

__global__ void k_prep_w(const float* __restrict__ Wih, const float* __restrict__ Whh_in,
                         unsigned short* __restrict__ Wx, unsigned short* __restrict__ Whh){
  int jp = blockIdx.x;
  int g = jp & 3, kr = jp >> 2;
  int j = g * NH + kr;
  int k = threadIdx.x * 4;
  float4 a = *(const float4*)(Wih + (size_t)j * (ND + NT) + k);
  float4 b = *(const float4*)(Whh_in + ((size_t)j << 10) + k);
  unsigned short* d1 = Wx + ((size_t)jp << 10) + k;
  unsigned short* d2 = Whh + ((size_t)jp << 10) + k;
  d1[0] = f2bf(a.x); d1[1] = f2bf(a.y); d1[2] = f2bf(a.z); d1[3] = f2bf(a.w);
  d2[0] = f2bf(b.x); d2[1] = f2bf(b.y); d2[2] = f2bf(b.z); d2[3] = f2bf(b.w);
}

__global__ void k_prep_tb(const float* __restrict__ Wih, const float* __restrict__ bih,
                          const float* __restrict__ bhh, float* __restrict__ Wtag,
                          float* __restrict__ biasc){
  int blk = blockIdx.x;
  for (int jp = threadIdx.x; jp < NG; jp += 256){
    int g = jp & 3, kr = jp >> 2;
    int j = g * NH + kr;
    if (blk < NT) Wtag[(size_t)blk * NG + jp] = Wih[(size_t)j * (ND + NT) + ND + blk];
    else          biasc[jp] = bih[j] + bhh[j];
  }
}

__global__ void k_prep_state(float* c, float* loss, unsigned* flags){
  int i = blockIdx.x * 256 + threadIdx.x;   // grid covers 131072
  c[i] = 0.f;
  if (i < 256) flags[(size_t)i * 512] = 0;
  if (i == 0) *loss = 0.f;
}

// x[b][s][d] f32 -> xb[(s*128+b)][d] bf16
__global__ void k_xpose(const float* __restrict__ x, unsigned short* __restrict__ xb){
  int r = blockIdx.x;
  int b = r & 127, s = r >> 7;
  int d = threadIdx.x * 4;
  float4 v = *(const float4*)(x + (((size_t)b * NS + s) << 10) + d);
  unsigned short* o = xb + ((size_t)r << 10) + d;
  o[0] = f2bf(v.x); o[1] = f2bf(v.y); o[2] = f2bf(v.z); o[3] = f2bf(v.w);
}

// ---------------- Gx precompute GEMM ----------------
__global__ __launch_bounds__(256, 2) void k_gemm_gx(const unsigned short* __restrict__ xb,
                                                    const unsigned short* __restrict__ Wx,
                                                    unsigned short* __restrict__ Gx, int row0){
  __shared__ unsigned short At[128 * 32];
  __shared__ unsigned short Bt[128 * 32];
  const int tid = threadIdx.x;
  const int wave = tid >> 6, lane = tid & 63;
  const int l15 = lane & 15, l4 = lane >> 4;
  const int wm = wave >> 1, wn = wave & 1;
  const int mloc = (int)blockIdx.x * 128;
  const int n0 = (int)blockIdx.y * 128;
  const unsigned short* Ab = xb + ((size_t)(row0 + mloc) << 10);
  const unsigned short* Bb = Wx + ((size_t)n0 << 10);

  v4f acc[4][4];
#pragma unroll
  for (int i = 0; i < 4; ++i)
#pragma unroll
    for (int j = 0; j < 4; ++j) acc[i][j] = (v4f){0.f, 0.f, 0.f, 0.f};

  for (int kk = 0; kk < 32; ++kk){
    const int k0 = kk * 32;
#pragma unroll
    for (int is = 0; is < 2; ++is){
      int c = is * 256 + tid;
      gload16(Ab + ((size_t)(c >> 2) << 10) + k0 + (c & 3) * 8, At + (is * 256 + wave * 64) * 8);
      gload16(Bb + ((size_t)(c >> 2) << 10) + k0 + (c & 3) * 8, Bt + (is * 256 + wave * 64) * 8);
    }
    __syncthreads();
    v8bf af[4], bfm[4];
#pragma unroll
    for (int i = 0; i < 4; ++i) af[i]  = *(const v8bf*)(At + (wm * 64 + i * 16 + l15) * 32 + l4 * 8);
#pragma unroll
    for (int j = 0; j < 4; ++j) bfm[j] = *(const v8bf*)(Bt + (wn * 64 + j * 16 + l15) * 32 + l4 * 8);
#pragma unroll
    for (int i = 0; i < 4; ++i)
#pragma unroll
      for (int j = 0; j < 4; ++j) acc[i][j] = mfma16x16x32(af[i], bfm[j], acc[i][j]);
    __syncthreads();
  }
#pragma unroll
  for (int i = 0; i < 4; ++i)
#pragma unroll
    for (int j = 0; j < 4; ++j){
      int r = mloc + wm * 64 + i * 16 + l4 * 4;
      int cc = n0 + wn * 64 + j * 16 + l15;
#pragma unroll
      for (int q = 0; q < 4; ++q) Gx[((size_t)(r + q) << 12) + cc] = f2bf(acc[i][j][q]);
    }
}

// ---------------- persistent step kernel ----------------

struct StepArgs {
  const unsigned short* Whh;   // [4096][1024] bf16 permuted (j' = 4k+gate)
  const unsigned short* Gx;    // [nsteps*128][4096] bf16
  const float* Wtag;           // [20][4096]
  const float* biasc;          // [4096]
  const float* Wout;           // [20][1024] f32
  const float* bout;           // [20]
  const int* tags;             // [128][256]
  const int* mask;             // [128][256]
  unsigned short* hh;          // [256*128][1024] bf16 h history (aliases xb)
  float* c;                    // [128][1024] f32 (chunk-boundary spill)
  float* loss;
  unsigned* flags;             // [4*64] producer flags, word stride 512 (2KB)
  int s0, nsteps;
};

// 256 wgs (1/CU), 512 threads. wg (bi,ni): 32 batch rows x 64 gate cols, K=1024.
__global__ __launch_bounds__(512, 1) void k_step(StepArgs A){
  __shared__ unsigned short hsl[32 * 1024];   // 64 KB h(s-1) slab (XOR-swizzled)
  __shared__ unsigned short wsl[64 * 512];    // 64 KB Whh slice, k<512 (XOR-swizzled)
  __shared__ float sred[8][32][21];           // 21.5 KB logits k-split partials
  __shared__ float sLog[32 * 21];             // summed logits
  __shared__ unsigned short sHW[32 * 16];     // h-out coalescing tile
  __shared__ int sPt[32];
  __shared__ float sBo[NT];
  const int tid = threadIdx.x;
  const int wave = tid >> 6, lane = tid & 63;
  const int l15 = lane & 15, l4 = lane >> 4;
  const int wm = wave >> 2, wn = wave & 3;
  const int bi = (int)blockIdx.x >> 6;
  const int ni = (int)blockIdx.x & 63;
  const int b0 = bi * 32;
  const int n0 = ni * 64;

  if (tid < NT) sBo[tid] = A.bout[tid];

  const int jl_f = wn * 16 + l15;
  const int jcol = n0 + jl_f;
  const int kh = jcol >> 2;
  const int bb = b0 + wm * 16 + l4 * 4;
  const float gb = A.biasc[jcol];
  const int qb = lane & ~3;
  const int bloc = wm * 16 + l4 * 4;        // b_local base
  const int khl = wn * 4 + (l15 >> 2);      // kh_local (valid on quad-lane-0)

  // gates A-fragment LDS addressing (row stride 2KB)
  const char* hbase = (const char*)hsl + ((size_t)(wm * 16 + l15) << 11);
  const unsigned hsw = (unsigned)((l15 & 7) << 4);
  // gates B LDS addressing (row stride 1KB, k<512 half)
  const char* wlbase = (const char*)wsl + ((size_t)jl_f << 10);
  const unsigned wsw = (unsigned)((jl_f & 7) << 4);

  // ---- stage Whh k<512 half into LDS once (swizzled) ----
  {
    int jl = tid >> 3;                // row 0..63
    int kc = (tid & 7) * 8;           // 16B-unit base 0..56
    const unsigned short* srcw = A.Whh + ((size_t)(n0 + jl) << 10) + kc * 8;
    char* dstw = (char*)wsl + ((size_t)jl << 10);
    const unsigned wsw2 = (unsigned)((jl & 7) << 4);
#pragma unroll
    for (int i = 0; i < 8; ++i){
      v8bf v = *(const v8bf*)(srcw + i * 8);
      *(v8bf*)(dstw + (((unsigned)((kc + i) * 16)) ^ wsw2)) = v;
    }
  }

  // ---- Whh k>=512 half in registers: 16 fragments (64 VGPR) ----
  v8bf Brg[16];
#pragma unroll
  for (int i = 0; i < 16; ++i)
    Brg[i] = *(const v8bf*)(A.Whh + ((size_t)jcol << 10) + 512 + i * 32 + l4 * 8);

  // ---- logits Wout B-fragments (bf16), k-split: wave handles kk = wave*4..+4 ----
  v8bf wfr0[4], wfr1[4];
  {
    const int kb = wave * 128 + l4 * 8;
#pragma unroll
    for (int nj = 0; nj < 2; ++nj){
      int t = nj * 16 + l15;
#pragma unroll
      for (int kkl = 0; kkl < 4; ++kkl){
        v8us uu = (v8us){0,0,0,0,0,0,0,0};
        if (t < NT){
          const float* wp = A.Wout + (size_t)t * NH + kb + kkl * 32;
          float4 w0 = *(const float4*)wp;
          float4 w1 = *(const float4*)(wp + 4);
          uu[0]=f2bf(w0.x); uu[1]=f2bf(w0.y); uu[2]=f2bf(w0.z); uu[3]=f2bf(w0.w);
          uu[4]=f2bf(w1.x); uu[5]=f2bf(w1.y); uu[6]=f2bf(w1.z); uu[7]=f2bf(w1.w);
        }
        v8bf w = __builtin_bit_cast(v8bf, uu);
        if (nj == 0) wfr0[kkl] = w; else wfr1[kkl] = w;
      }
    }
  }

  float creg[4];
  if ((lane & 3) == 0){
#pragma unroll
    for (int q = 0; q < 4; ++q) creg[q] = A.c[((size_t)(bb + q) << 10) + kh];
  }
  float lacc = 0.f;

  // Gx raw prologue for sl = 0
  unsigned short gxraw[4];
  {
    const unsigned short* g0 = A.Gx + jcol;
#pragma unroll
    for (int q = 0; q < 4; ++q) gxraw[q] = g0[(size_t)(bb + q) * NG];
  }

  // ---- prologue: stage h(s0-1) into hsl (zeros if s0==0) ----
  const int sr = tid & 31;
  const int sseg = tid >> 5;
  char* const sdst = (char*)hsl + ((size_t)sr << 11);
  const unsigned ssw = (unsigned)((sr & 7) << 4);
  if (A.s0 == 0){
    v4u z = (v4u){0,0,0,0};
#pragma unroll
    for (int i = 0; i < 8; ++i)
      *(v4u*)(sdst + (((unsigned)(sseg * 128 + i * 16)) ^ ssw)) = z;
  } else {
    const unsigned short* src = A.hh + ((size_t)((A.s0 - 1) * NB + b0 + sr) << 10) + sseg * 64;
    v4u st[8];
#pragma unroll
    for (int i = 0; i < 8; ++i) st[i] = bypass_ld16(src + i * 8);
    DRAIN_VM();
#pragma unroll
    for (int i = 0; i < 8; ++i)
      *(v4u*)(sdst + (((unsigned)(sseg * 128 + i * 16)) ^ ssw)) = st[i];
  }
  __syncthreads();   // hsl + wsl + sBo ready

  for (int sl = 0; sl < A.nsteps; ++sl){
    const int s = A.s0 + sl;

    // ---- 1. logits(s-1) MFMA, k-split over waves -> sred ----
    v4f d00 = (v4f){0,0,0,0}, d01 = (v4f){0,0,0,0};
    v4f d10 = (v4f){0,0,0,0}, d11 = (v4f){0,0,0,0};
#pragma unroll
    for (int kkl = 0; kkl < 4; ++kkl){
      const unsigned ko = (unsigned)((wave * 4 + kkl) * 64 + l4 * 16);
      v8bf a0 = *(const v8bf*)((const char*)hsl + ((size_t)l15 << 11) + (ko ^ ((l15 & 7) << 4)));
      v8bf a1 = *(const v8bf*)((const char*)hsl + ((size_t)(16 + l15) << 11) + (ko ^ ((l15 & 7) << 4)));
      d00 = mfma16x16x32(a0, wfr0[kkl], d00);
      d10 = mfma16x16x32(a1, wfr0[kkl], d10);
      d01 = mfma16x16x32(a0, wfr1[kkl], d01);
      d11 = mfma16x16x32(a1, wfr1[kkl], d11);
    }
    {
      const int rb = l4 * 4;
#pragma unroll
      for (int q = 0; q < 4; ++q){
        sred[wave][rb + q][l15]      = d00[q];
        sred[wave][16 + rb + q][l15] = d10[q];
      }
      if (l15 < 4){
#pragma unroll
        for (int q = 0; q < 4; ++q){
          sred[wave][rb + q][16 + l15]      = d01[q];
          sred[wave][16 + rb + q][16 + l15] = d11[q];
        }
      }
    }

    // ---- 2. gates GEMM: A from hsl; B from wsl (k<512) + Brg (k>=512) ----
    v4f acc = (v4f){0,0,0,0};
#pragma unroll
    for (int kk = 0; kk < 16; ++kk){
      v8bf a = *(const v8bf*)(hbase + (((unsigned)(kk * 64 + l4 * 16)) ^ hsw));
      v8bf b = *(const v8bf*)(wlbase + (((unsigned)(kk * 64 + l4 * 16)) ^ wsw));
      acc = mfma16x16x32(a, b, acc);
    }
#pragma unroll
    for (int kk = 16; kk < 32; ++kk){
      v8bf a = *(const v8bf*)(hbase + (((unsigned)(kk * 64 + l4 * 16)) ^ hsw));
      acc = mfma16x16x32(a, Brg[kk - 16], acc);
    }
    __syncthreads();   // sred complete

    // ---- 4. k-reduce + bias -> sLog ----
    for (int idx = tid; idx < 32 * NT; idx += 512){
      int b = idx / NT, t = idx - b * NT;
      float v = sBo[t];
#pragma unroll
      for (int w8 = 0; w8 < 8; ++w8) v += sred[w8][b][t];
      sLog[b * 21 + t] = v;
    }
    __syncthreads();   // sLog ready

    // ---- 6. argmax -> sPt ; CE loss(s-1) by designated wg ----
    if (tid < 32){
      int pt = START_IDX_;
      if (s > 0){
        const float* lr = sLog + tid * 21;
        float mv = lr[0]; pt = 0;
#pragma unroll
        for (int t = 1; t < NT; ++t){ float v = lr[t]; if (v > mv){ mv = v; pt = t; } }
      }
      sPt[tid] = pt;
    }
    if (ni == 16 && tid >= 64 && tid < 96 && s > 0){
      int bl = tid - 64;
      int b = b0 + bl;
      int tg = A.tags[(size_t)b * NS + (s - 1)];
      int mk = A.mask[(size_t)b * NS + (s - 1)];
      if (mk != 0){
        const float* lr = sLog + bl * 21;
        float mv = lr[0];
#pragma unroll
        for (int t = 1; t < NT; ++t) mv = fmaxf(mv, lr[t]);
        float se = 0.f;
#pragma unroll
        for (int t = 0; t < NT; ++t) se += __expf(lr[t] - mv);
        lacc += mv + __logf(se) - lr[tg];
      }
    }
    __syncthreads();   // sPt ready

    // ---- 8. finish gates, update c/h ----
    float wtv[4];
#pragma unroll
    for (int q = 0; q < 4; ++q)
      wtv[q] = A.Wtag[(size_t)sPt[bloc + q] * NG + jcol];
    float gv[4];
#pragma unroll
    for (int q = 0; q < 4; ++q)
      gv[q] = acc[q] + gb + bf2f(gxraw[q]) + wtv[q];
#pragma unroll
    for (int q = 0; q < 4; ++q){
      float iv = __shfl(gv[q], qb + 0);
      float fv = __shfl(gv[q], qb + 1);
      float gg = __shfl(gv[q], qb + 2);
      float ov = __shfl(gv[q], qb + 3);
      if ((lane & 3) == 0){
        float cn = sigm(fv) * creg[q] + sigm(iv) * tanhf_(gg);
        float hn = sigm(ov) * tanhf_(cn);
        creg[q] = cn;
        sHW[(bloc + q) * 16 + khl] = f2bf(hn);
      }
    }
    __syncthreads();   // sHW ready

    // ---- 11. coalesced h(s) store (wg owns 16 consecutive k-units) ----
    if (tid < 128){
      int r = tid >> 2, seg = tid & 3;
      unsigned long long uv = *(const unsigned long long*)(sHW + r * 16 + seg * 4);
      bypass_st8(A.hh + ((size_t)(s * NB + b0 + r) << 10) + (n0 >> 2) + seg * 4,
                 __builtin_bit_cast(v2u, uv));
      DRAIN_VM();
    }
    __syncthreads();   // all h stores drained

    // ---- 13. flag + poll + load h(s) + Gx prefetch ----
    if (sl + 1 < A.nsteps){
      if (wave == 0){
        if (lane == 0)
          bypass_st4(A.flags + ((unsigned)(bi * 64 + ni)) * 512u, (unsigned)(s + 1));
        const unsigned* mf = A.flags + ((unsigned)(bi * 64) + lane) * 512u;
        while (true){
          unsigned v = bypass_ld4_wait(mf);
          if (__all((int)(v >= (unsigned)(s + 1)))) break;
          __builtin_amdgcn_s_sleep(1);
        }
      }
      __syncthreads();   // h(s) globally ready
      const unsigned short* src = A.hh + ((size_t)(s * NB + b0 + sr) << 10) + sseg * 64;
      v4u st[8];
#pragma unroll
      for (int i = 0; i < 8; ++i) st[i] = bypass_ld16(src + i * 8);
      const unsigned short* gn = A.Gx + (size_t)(sl + 1) * NB * NG + jcol;
#pragma unroll
      for (int q = 0; q < 4; ++q) gxraw[q] = gn[(size_t)(bb + q) * NG];
      DRAIN_VM();
#pragma unroll
      for (int i = 0; i < 8; ++i)
        *(v4u*)(sdst + (((unsigned)(sseg * 128 + i * 16)) ^ ssw)) = st[i];
      __syncthreads();   // hsl = h(s) ready
    } else {
      if (tid == 0)
        bypass_st4(A.flags + ((unsigned)(bi * 64 + ni)) * 512u, (unsigned)(s + 1));
    }
  }

  // epilogue: spill c for chunk boundary, flush loss once
  if ((lane & 3) == 0){
#pragma unroll
    for (int q = 0; q < 4; ++q) A.c[((size_t)(bb + q) << 10) + kh] = creg[q];
  }
  if (ni == 16 && tid >= 64 && tid < 96) atomicAdd(A.loss, lacc);
}

// final: logits + CE for step NS-1 (h(NS-1) lives in hh history), plus accumulated loss
__global__ __launch_bounds__(1024) void k_final(const unsigned short* __restrict__ hlast,
                        const float* __restrict__ Wout, const float* __restrict__ bout,
                        const int* __restrict__ tags, const int* __restrict__ mask,
                        const float* __restrict__ loss, float* __restrict__ out){
  __shared__ float fl[NB * NT];
  __shared__ float red[NB];
  const int tid = threadIdx.x;
  for (int idx = tid; idx < NB * NT; idx += 1024){
    int b = idx / NT, t = idx - b * NT;
    const unsigned short* hp = hlast + ((size_t)b << 10);
    const float* wp = Wout + (size_t)t * NH;
    float acc = 0.f;
    for (int k = 0; k < NH; k += 8){
      ushort4 h0 = *(const ushort4*)(hp + k);
      ushort4 h1 = *(const ushort4*)(hp + k + 4);
      float4 w0 = *(const float4*)(wp + k);
      float4 w1 = *(const float4*)(wp + k + 4);
      acc += bf2f(h0.x)*w0.x + bf2f(h0.y)*w0.y + bf2f(h0.z)*w0.z + bf2f(h0.w)*w0.w
           + bf2f(h1.x)*w1.x + bf2f(h1.y)*w1.y + bf2f(h1.z)*w1.z + bf2f(h1.w)*w1.w;
    }
    fl[idx] = acc + bout[t];
  }
  __syncthreads();
  if (tid < NB){
    const float* lr = fl + tid * NT;
    int tg = tags[(size_t)tid * NS + (NS - 1)];
    int mk = mask[(size_t)tid * NS + (NS - 1)];
    float v = 0.f;
    if (mk != 0){
      float mv = lr[0];
      for (int t = 1; t < NT; ++t) mv = fmaxf(mv, lr[t]);
      float se = 0.f;
      for (int t = 0; t < NT; ++t) se += __expf(lr[t] - mv);
      v = mv + __logf(se) - lr[tg];
    }
    red[tid] = v;
  }
  __syncthreads();
  if (tid == 0){
    float tot = *loss;
    for (int i = 0; i < NB; ++i) tot += red[i];
    out[0] = tot;
  }
}

// ---------------- host ----------------

extern "C" void kernel_launch(void* const* d_in, const int* in_sizes, int n_in,
                              void* d_out, int out_size, void* d_ws, size_t ws_size,
                              hipStream_t stream){
  const float* x      = (const float*)d_in[0];
  const int*   tags   = (const int*)  d_in[1];
  const int*   mask   = (const int*)  d_in[2];
  const float* Wih    = (const float*)d_in[3];
  const float* Whh_in = (const float*)d_in[4];
  const float* bih    = (const float*)d_in[5];
  const float* bhh    = (const float*)d_in[6];
  const float* Wout   = (const float*)d_in[7];
  const float* bout   = (const float*)d_in[8];

  char* base = (char*)d_ws;
  size_t off = 0;
  auto alloc = [&](size_t bytes) -> char* {
    char* p = base + off;
    off = (off + bytes + 255) & ~(size_t)255;
    return p;
  };
  unsigned short* Wx    = (unsigned short*)alloc((size_t)NG * NH * 2);
  unsigned short* Whh   = (unsigned short*)alloc((size_t)NG * NH * 2);
  float*          Wtag  = (float*)alloc((size_t)NT * NG * 4);
  float*          biasc = (float*)alloc((size_t)NG * 4);
  float*          c     = (float*)alloc((size_t)NB * NH * 4);
  float*          loss  = (float*)alloc(256);
  unsigned*       flags = (unsigned*)alloc((size_t)256 * 2048 + 256);
  unsigned short* xb    = (unsigned short*)alloc((size_t)NS * NB * NH * 2);  // doubles as h history

  size_t fixed = off;
  int schunk = NS;
  while (schunk > 1 && fixed + (size_t)schunk * NB * NG * 2 > ws_size) schunk >>= 1;
  unsigned short* Gx = (unsigned short*)alloc((size_t)schunk * NB * NG * 2);

  k_prep_w<<<NG, 256, 0, stream>>>(Wih, Whh_in, Wx, Whh);
  k_prep_tb<<<NT + 1, 256, 0, stream>>>(Wih, bih, bhh, Wtag, biasc);
  k_prep_state<<<(NB * NH) / 256, 256, 0, stream>>>(c, loss, flags);
  k_xpose<<<NS * NB, 256, 0, stream>>>(x, xb);

  int done = 0;
  while (done < NS){
    int ns = (NS - done < schunk) ? (NS - done) : schunk;
    k_gemm_gx<<<dim3(ns, 32), 256, 0, stream>>>(xb, Wx, Gx, done * NB);
    StepArgs sa;
    sa.Whh = Whh; sa.Gx = Gx; sa.Wtag = Wtag; sa.biasc = biasc;
    sa.Wout = Wout; sa.bout = bout; sa.tags = tags; sa.mask = mask;
    sa.hh = xb; sa.c = c;
    sa.loss = loss; sa.flags = flags; sa.s0 = done; sa.nsteps = ns;
    hipLaunchKernelGGL(k_step, dim3(NBLK), dim3(512), 0, stream, sa);
    done += ns;
  }
  k_final<<<1, 1024, 0, stream>>>(xb + ((size_t)((NS - 1) * NB) << 10),
                                  Wout, bout, tags, mask, loss, (float*)d_out);
}